// Round 8
// baseline (173.987 us; speedup 1.0000x reference)
//
#include <hip/hip_runtime.h>

// DenseDilatedKnnGraphDGL: B=64, C=256, N=1024, layer_idx=8 -> dilation=3, k=9, k_d=27
// out[0:589824]       = src_d (int32): rank-{0,3,..,24} neighbor index + b*N
// out[589824:1179648] = dst_d (int32): j/9
//
// R8: trans rebuilt on global_load_lds (knn unchanged from R7):
//  - 2048 blocks (b x 32-col chunk); stage 32KB fp32 [256c x 32n] into LDS
//    via async DMA (8 instrs/wave, no VGPR latency chain), one barrier, then
//    per-thread c-contiguous gather (XOR-swizzled -> 2-way banks = free),
//    bf16 convert, 64B/lane coalesced writes, shfl-reduced fp32 norms.
//  - swizzle sigma(c) = (c ^ (c>>5)) & 7 permutes the SOURCE n-quad per lane,
//    keeping the DMA dest contiguous while making reads conflict-free.

typedef __bf16 bf16x8 __attribute__((ext_vector_type(8)));
typedef float  f32x4  __attribute__((ext_vector_type(4)));
typedef unsigned int u32;

#define B_   64
#define C_   256
#define N_   1024
#define NSRC (B_ * N_ * 9)   // 589824

#define STRIDE_I 1088        // knn staging: 1024 + 64B pad between instructions
#define REGION_W 8704        // 8 * STRIDE_I per wave-region (16 rows)

__device__ __forceinline__ u32 umin_(u32 a, u32 b) { return a < b ? a : b; }
__device__ __forceinline__ u32 umax_(u32 a, u32 b) { return a > b ? a : b; }

__device__ __forceinline__ void load_lds16(const void* g, void* l) {
    __builtin_amdgcn_global_load_lds((const __attribute__((address_space(1))) void*)g,
                                     (__attribute__((address_space(3))) void*)l,
                                     16, 0, 0);
}

// ---------------------------------------------------------------------------
// Kernel 1: async-staged transpose + fp32->bf16 + row norms.
// grid 2048 = 64 b x 32 n-chunks of 32; block 256 (4 waves).
// Stage: wave w, instr i: 8 c-rows (cbase = w*64+i*8) x 32 n (128B/row);
//   lane l -> c = cbase + (l>>3), source n-quad = (l&7) ^ sigma(c).
//   LDS unit (c*8 + u) holds n-quad (u ^ sigma(c)).  [32KB, no pad]
// Read: thread (n'=tid>>3, p=tid&7): c = 32p+j (j=0..31) at unit c*8 +
//   ((n'>>2) ^ sigma(c)), word +(n'&3) -> bank 4*swz+(n'&3): exactly 2-way.
__global__ __launch_bounds__(256, 4) void trans_kernel(const float* __restrict__ X,
                                                       unsigned short* __restrict__ XT,
                                                       float* __restrict__ NRM) {
    __shared__ __align__(1024) float S[8192];   // 32KB
    const int tid  = threadIdx.x;
    const int lane = tid & 63;
    const int w    = tid >> 6;
    const int b    = blockIdx.x >> 5;
    const int n0   = (blockIdx.x & 31) * 32;

    // ---- stage: 32 instrs (8 per wave) ----
    {
        const int cl  = lane >> 3;                      // c offset within 8-row group
        const int q0  = lane & 7;                       // dest n-quad slot
        const char* gb = (const char*)(X + ((size_t)b * C_) * N_ + n0);
#pragma unroll
        for (int i = 0; i < 8; ++i) {
            const int c   = w * 64 + i * 8 + cl;
            const int sig = (c ^ (c >> 5)) & 7;
            const int nq  = q0 ^ sig;                   // swizzled source quad
            load_lds16(gb + (size_t)c * 4096 + nq * 16,
                       (char*)S + (size_t)(w * 512 + i * 64) * 16);
        }
    }
    __syncthreads();

    // ---- convert + write + norm ----
    {
        const int np = tid >> 3;          // 0..31 : output row n0+np
        const int p  = tid & 7;           // c-block of 32
        u32 pk[16];
        float nsq = 0.f;
        const int hi4 = (np >> 2) & 7;
        const int lo2 = np & 3;
#pragma unroll
        for (int j = 0; j < 32; ++j) {
            const int c   = p * 32 + j;
            const int sig = (c ^ (c >> 5)) & 7;
            float f = S[(c * 8 + (hi4 ^ sig)) * 4 + lo2];
            nsq = fmaf(f, f, nsq);
            u32 u  = __float_as_uint(f);
            u32 bf = (u + 0x7FFFu + ((u >> 16) & 1u)) >> 16;   // RNE to bf16
            if ((j & 1) == 0) pk[j >> 1] = bf;
            else              pk[j >> 1] |= (bf << 16);
        }
        uint4* dst = (uint4*)(XT + ((size_t)b * N_ + n0 + np) * C_ + p * 32);
#pragma unroll
        for (int j = 0; j < 4; ++j)
            dst[j] = make_uint4(pk[4 * j], pk[4 * j + 1], pk[4 * j + 2], pk[4 * j + 3]);

        nsq += __shfl_xor(nsq, 1);
        nsq += __shfl_xor(nsq, 2);
        nsq += __shfl_xor(nsq, 4);
        if (p == 0) NRM[b * N_ + n0 + np] = nsq;
    }
}

// ---------------------------------------------------------------------------
// bitonic-merge of a bitonic 8-seq in regs -> ascending (phases j=4,2,1)
#define SORT8(v)                                                              \
    do {                                                                      \
        u32 mn, mx;                                                           \
        mn = umin_(v[0], v[4]); mx = umax_(v[0], v[4]); v[0] = mn; v[4] = mx; \
        mn = umin_(v[1], v[5]); mx = umax_(v[1], v[5]); v[1] = mn; v[5] = mx; \
        mn = umin_(v[2], v[6]); mx = umax_(v[2], v[6]); v[2] = mn; v[6] = mx; \
        mn = umin_(v[3], v[7]); mx = umax_(v[3], v[7]); v[3] = mn; v[7] = mx; \
        mn = umin_(v[0], v[2]); mx = umax_(v[0], v[2]); v[0] = mn; v[2] = mx; \
        mn = umin_(v[1], v[3]); mx = umax_(v[1], v[3]); v[1] = mn; v[3] = mx; \
        mn = umin_(v[4], v[6]); mx = umax_(v[4], v[6]); v[4] = mn; v[6] = mx; \
        mn = umin_(v[5], v[7]); mx = umax_(v[5], v[7]); v[5] = mn; v[7] = mx; \
        mn = umin_(v[0], v[1]); mx = umax_(v[0], v[1]); v[0] = mn; v[1] = mx; \
        mn = umin_(v[2], v[3]); mx = umax_(v[2], v[3]); v[2] = mn; v[3] = mx; \
        mn = umin_(v[4], v[5]); mx = umax_(v[4], v[5]); v[4] = mn; v[5] = mx; \
        mn = umin_(v[6], v[7]); mx = umax_(v[6], v[7]); v[6] = mn; v[7] = mx; \
    } while (0)

// Kernel 2: MFMA distances (shared LDS staging) + exact distributed top-32.
// grid 1024 = 64 b x 16 query-chunks of 64; block 256 (4 waves); 4 blocks/CU.
// (unchanged from R7)
__global__ __launch_bounds__(256, 4) void knn_mfma_kernel(const unsigned short* __restrict__ XT,
                                                          const float* __restrict__ NRM,
                                                          int* __restrict__ out) {
    __shared__ __align__(1024) char Bt[4 * REGION_W];   // 34816 B

    const int tid  = threadIdx.x;
    const int lane = tid & 63;
    const int w    = tid >> 6;

    const int bi = blockIdx.x;
    const int b  = (bi & 7) + 8 * (bi >> 7);     // batch-locality swizzle (mod-8)
    const int n0 = ((bi >> 3) & 15) * 64;        // query base (64 queries/block)

    const int lrow = lane & 15;
    const int g    = lane >> 4;
    const bool odd = lane & 1;
    const bool hiP = (lane >> 1) & 1;

    const unsigned short* xtb = XT + (size_t)b * N_ * C_;
    const float* nrmb = NRM + b * N_;

    // A fragments: wave w's 16 queries (rows n0 + w*16 + lrow), full K=256
    bf16x8 afr[8];
    {
        const unsigned short* ap = xtb + (n0 + w * 16 + lrow) * C_ + g * 8;
#pragma unroll
        for (int kc = 0; kc < 8; ++kc)
            afr[kc] = *(const bf16x8*)(ap + kc * 32);
    }

    // per-round per-lane sorted top-6 lists (ascending)
    u32 L[4][6];
#pragma unroll
    for (int r = 0; r < 4; ++r)
#pragma unroll
        for (int i = 0; i < 6; ++i) L[r][i] = 0xFFFFFFFFu;

    char* const ldsw = Bt + w * REGION_W;   // this wave's staging region
    const int lh   = lane >> 5;
    const int col0 = (lane & 31) * 16;

#pragma unroll 1
    for (int c = 0; c < 16; ++c) {
        // ---- stage: wave w stages rows c*64 + w*16 .. +16 (8KB) ----
        {
            const char* gb = (const char*)(xtb + (size_t)(c * 64 + w * 16) * C_);
#pragma unroll
            for (int i = 0; i < 8; ++i) {
                const int rt  = i * 2 + lh;                  // row within 16-block
                const int col = (col0 - rt * 16) & 511;      // inverse rotation
                load_lds16(gb + (size_t)rt * 512 + col, ldsw + i * STRIDE_I);
            }
        }
        __syncthreads();

        // ---- compute: 4 tiles (w*16 queries x 64 points) ----
#pragma unroll
        for (int t = 0; t < 4; ++t) {
            const char* rbase = Bt + t * REGION_W + (lrow >> 1) * STRIDE_I + (lrow & 1) * 512;
            f32x4 acc = {0.f, 0.f, 0.f, 0.f};
#pragma unroll
            for (int kc = 0; kc < 8; ++kc) {
                bf16x8 bfr = *(const bf16x8*)(rbase + ((kc * 64 + g * 16 + lrow * 16) & 511));
                acc = __builtin_amdgcn_mfma_f32_16x16x32_bf16(afr[kc], bfr, acc, 0, 0, 0);
            }
            const int m = c * 64 + t * 16 + lrow;
            const float nm = nrmb[m];
#pragma unroll
            for (int r = 0; r < 4; ++r) {
                float f = fmaf(-2.f, acc[r], nm);              // d2 minus row-const
                u32 u = __float_as_uint(f);
                u = u ^ ((u32)((int)u >> 31) | 0x80000000u);   // monotonic float->uint
                u32 cur = (u & 0xFFFFFC00u) | (u32)m;          // index in low 10 bits
#pragma unroll
                for (int i = 0; i < 6; ++i) {
                    u32 lo = umin_(L[r][i], cur);
                    u32 hi = umax_(L[r][i], cur);
                    L[r][i] = lo; cur = hi;
                }
            }
        }
        __syncthreads();
    }

    // ---- selection: exact distributed top-32 per query row (row = 4g+r) ----
    int* out_src = out;
    int* out_dst = out + NSRC;
#pragma unroll
    for (int r = 0; r < 4; ++r) {
        u32 v[8], t1[8];
#pragma unroll
        for (int i = 0; i < 6; ++i) v[i] = L[r][i];
        v[6] = 0xFFFFFFFFu; v[7] = 0xFFFFFFFFu;

        // S1: pair merge, keep all 16 (e: ranks 0-7, o: 8-15)
#pragma unroll
        for (int i = 0; i < 8; ++i) t1[i] = __shfl_xor(v[i], 1);
#pragma unroll
        for (int i = 0; i < 8; ++i) {
            u32 mn = umin_(v[i], t1[7 - i]);
            u32 mx = umax_(v[i], t1[7 - i]);
            v[i] = odd ? mx : mn;
        }
        SORT8(v);

        // S2: full merge of two pair-16s -> sorted-32 over quad
#pragma unroll
        for (int i = 0; i < 8; ++i) t1[i] = __shfl_xor(v[i], 3);
#pragma unroll
        for (int i = 0; i < 8; ++i) {
            u32 mn = umin_(v[i], t1[7 - i]);
            u32 mx = umax_(v[i], t1[7 - i]);
            v[i] = hiP ? mx : mn;
        }
#pragma unroll
        for (int i = 0; i < 8; ++i) t1[i] = __shfl_xor(v[i], 1);
#pragma unroll
        for (int i = 0; i < 8; ++i)
            v[i] = odd ? umax_(v[i], t1[i]) : umin_(v[i], t1[i]);
        SORT8(v);

        // S3 (dist 4) and S4 (dist 8): keep-32 of 64, then clean-32
#pragma unroll
        for (int s = 0; s < 2; ++s) {
            const int mask = s ? 11 : 7;   // flip {quad|octet}, pp, p
#pragma unroll
            for (int i = 0; i < 8; ++i) t1[i] = __shfl_xor(v[i], mask);
#pragma unroll
            for (int i = 0; i < 8; ++i) v[i] = umin_(v[i], t1[7 - i]);   // keep-32
            // clean: j=16 (pp), j=8 (parity), then in-lane
#pragma unroll
            for (int i = 0; i < 8; ++i) t1[i] = __shfl_xor(v[i], 2);
#pragma unroll
            for (int i = 0; i < 8; ++i)
                v[i] = hiP ? umax_(v[i], t1[i]) : umin_(v[i], t1[i]);
#pragma unroll
            for (int i = 0; i < 8; ++i) t1[i] = __shfl_xor(v[i], 1);
#pragma unroll
            for (int i = 0; i < 8; ++i)
                v[i] = odd ? umax_(v[i], t1[i]) : umin_(v[i], t1[i]);
            SORT8(v);
        }

        // output: quad 0 of each group holds sorted top-32; rank = 16*pp+8*p+i
        if ((lane & 12) == 0) {
            const int rank0 = (hiP ? 16 : 0) + (odd ? 8 : 0);
            const int obase = (b * N_ + n0 + w * 16 + 4 * g + r) * 9;
#pragma unroll
            for (int i = 0; i < 8; ++i) {
                const int rank = rank0 + i;
                if (rank < 25 && (rank % 3) == 0)
                    out_src[obase + rank / 3] = (b << 10) | (int)(v[i] & 1023u);
            }
        }
    }

    // ---- dst for this block: 64 queries * 9 = 576 ----
    const int jbase = (b * N_ + n0) * 9;
    for (int idx = tid; idx < 576; idx += 256)
        out_dst[jbase + idx] = (jbase + idx) / 9;
}

// ---------------------------------------------------------------------------
// Fallback (R1 kernel) if workspace is too small for XT+NRM
__global__ __launch_bounds__(256, 2) void knn_kernel(const float* __restrict__ X,
                                                     int* __restrict__ out) {
    __shared__ float smem[16 * N_];
    const int tid = threadIdx.x;
    const int b  = blockIdx.x >> 6;
    const int n0 = (blockIdx.x & 63) * 16;
    const float* __restrict__ xb = X + (size_t)b * C_ * N_;
#pragma unroll
    for (int i = 0; i < 16; ++i) {
        int f = tid + i * 256;
        int c = f >> 4, qq = f & 15;
        smem[f] = xb[c * N_ + n0 + qq];
    }
    __syncthreads();
    float acc[16][4];
#pragma unroll
    for (int q = 0; q < 16; ++q) { acc[q][0] = acc[q][1] = acc[q][2] = acc[q][3] = 0.f; }
    float nrm[4] = {0.f, 0.f, 0.f, 0.f};
    for (int c = 0; c < C_; ++c) {
        const float* __restrict__ xc = xb + c * N_;
        float bv0 = xc[tid], bv1 = xc[tid + 256], bv2 = xc[tid + 512], bv3 = xc[tid + 768];
        const float4* A4 = reinterpret_cast<const float4*>(smem + c * 16);
        float4 a0 = A4[0], a1 = A4[1], a2 = A4[2], a3 = A4[3];
        float aq[16] = {a0.x, a0.y, a0.z, a0.w, a1.x, a1.y, a1.z, a1.w,
                        a2.x, a2.y, a2.z, a2.w, a3.x, a3.y, a3.z, a3.w};
#pragma unroll
        for (int q = 0; q < 16; ++q) {
            acc[q][0] = fmaf(aq[q], bv0, acc[q][0]);
            acc[q][1] = fmaf(aq[q], bv1, acc[q][1]);
            acc[q][2] = fmaf(aq[q], bv2, acc[q][2]);
            acc[q][3] = fmaf(aq[q], bv3, acc[q][3]);
        }
        nrm[0] = fmaf(bv0, bv0, nrm[0]); nrm[1] = fmaf(bv1, bv1, nrm[1]);
        nrm[2] = fmaf(bv2, bv2, nrm[2]); nrm[3] = fmaf(bv3, bv3, nrm[3]);
    }
    __syncthreads();
#pragma unroll
    for (int q = 0; q < 16; ++q) {
        smem[q * N_ + tid]       = nrm[0] - 2.f * acc[q][0];
        smem[q * N_ + tid + 256] = nrm[1] - 2.f * acc[q][1];
        smem[q * N_ + tid + 512] = nrm[2] - 2.f * acc[q][2];
        smem[q * N_ + tid + 768] = nrm[3] - 2.f * acc[q][3];
    }
    __syncthreads();
    const int lane = tid & 63;
    const int w    = tid >> 6;
    int* out_src = out;
    int* out_dst = out + NSRC;
    for (int q = w; q < 16; q += 4) {
        float v[16];
#pragma unroll
        for (int i = 0; i < 16; ++i) v[i] = smem[q * N_ + lane + i * 64];
        float lv = v[0]; int ls = 0;
#pragma unroll
        for (int i = 1; i < 16; ++i) { if (v[i] < lv) { lv = v[i]; ls = i; } }
        int lm = lane + (ls << 6);
        const int obase = (b * N_ + n0 + q) * 9;
#pragma unroll
        for (int r = 0; r < 25; ++r) {
            float bv = lv; int bm = lm;
#pragma unroll
            for (int off = 32; off >= 1; off >>= 1) {
                float ov = __shfl_xor(bv, off);
                int   om = __shfl_xor(bm, off);
                if (ov < bv || (ov == bv && om < bm)) { bv = ov; bm = om; }
            }
            if ((r % 3) == 0 && lane == 0) out_src[obase + r / 3] = b * N_ + bm;
            if (bm == lm) {
#pragma unroll
                for (int i = 0; i < 16; ++i) { if (i == ls) v[i] = 3.4e38f; }
                lv = v[0]; ls = 0;
#pragma unroll
                for (int i = 1; i < 16; ++i) { if (v[i] < lv) { lv = v[i]; ls = i; } }
                lm = lane + (ls << 6);
            }
        }
    }
    const int jbase = (b * N_ + n0) * 9;
    if (tid < 16 * 9) out_dst[jbase + tid] = (jbase + tid) / 9;
}

extern "C" void kernel_launch(void* const* d_in, const int* in_sizes, int n_in,
                              void* d_out, int out_size, void* d_ws, size_t ws_size,
                              hipStream_t stream) {
    (void)in_sizes; (void)n_in; (void)out_size;
    const float* X = (const float*)d_in[0];
    int* out = (int*)d_out;
    const size_t xt_bytes  = (size_t)B_ * N_ * C_ * 2;   // 33,554,432
    const size_t nrm_bytes = (size_t)B_ * N_ * 4;        // 262,144
    if (ws_size >= xt_bytes + nrm_bytes) {
        unsigned short* XT = (unsigned short*)d_ws;
        float* NRM = (float*)((char*)d_ws + xt_bytes);
        trans_kernel<<<dim3(B_ * 32), dim3(256), 0, stream>>>(X, XT, NRM);
        knn_mfma_kernel<<<dim3(B_ * 16), dim3(256), 0, stream>>>(XT, NRM, out);
    } else {
        knn_kernel<<<dim3(B_ * 64), dim3(256), 0, stream>>>(X, out);
    }
}